// Round 4
// baseline (162.557 us; speedup 1.0000x reference)
//
#include <hip/hip_runtime.h>
#include <math.h>

#define NCAM 6
#define C_CH 64
#define HF   64
#define WF   176
#define GDIM 129
#define NY   4
#define NH   3
#define DD   128
#define WDIM 128
#define NP   (DD*WDIM)

// BoxP: 4 precombined byte offsets into the quad buffer (corner sample points),
// 4 lerp weights, gated area. 48B, uniform-loaded once per (cam,voxel) per wave.
struct alignas(16) BoxP {
    int   oTL, oTR, oBL, oBR;   // byte offsets of quad texels (y*WF+x)*C_CH*16
    float wxL, wxR, wyT, wyB;
    float area;
    int   pad0, pad1, pad2;
};
static_assert(sizeof(BoxP) == 48, "BoxP size");

__device__ __forceinline__ int rfl_i(int x) {
    return __builtin_amdgcn_readfirstlane(x);
}
__device__ __forceinline__ float rfl_f(float x) {
    return __builtin_bit_cast(float, __builtin_amdgcn_readfirstlane(__builtin_bit_cast(int, x)));
}

// ---------------- Kernel 1: row cumsum (axis=-1) -> channel-last rowsum ----------------
__global__ __launch_bounds__(256) void k_rowcum(const float* __restrict__ feat,
                                                float* __restrict__ rowsum)
{
    __shared__ float T[WF * 65];
    __shared__ float S[4][C_CH];
    __shared__ float OFF[4][C_CH];
    const int h   = blockIdx.x;
    const int n   = blockIdx.y;
    const int tid = threadIdx.x;

    for (int idx = tid; idx < C_CH * WF; idx += 256) {
        const int cc = idx / WF;
        const int w  = idx % WF;
        T[w*65 + cc] = feat[((size_t)(n*C_CH + cc)*HF + h)*WF + w];
    }
    __syncthreads();
    {
        const int cc = tid & 63, seg = tid >> 6;
        const int w0 = seg * 44;
        float run = 0.0f;
        #pragma unroll
        for (int i = 0; i < 44; ++i) {
            run += T[(w0 + i)*65 + cc];
            T[(w0 + i)*65 + cc] = run;
        }
        S[seg][cc] = run;
    }
    __syncthreads();
    {
        const int cc = tid & 63, seg = tid >> 6;
        float off = 0.0f;
        #pragma unroll
        for (int s = 0; s < 3; ++s)
            if (s < seg) off += S[s][cc];
        OFF[seg][cc] = off;
    }
    __syncthreads();
    float* outp = rowsum + (size_t)(n*HF + h) * (WF * C_CH);
    for (int idx = tid; idx < WF * C_CH; idx += 256) {
        const int w  = idx >> 6;
        const int cc = idx & 63;
        outp[idx] = T[w*65 + cc] + OFF[w/44][cc];
    }
}

// ---------------- Kernel 2: column cumsum + quad-texel emission (register scan) ----------
// Block per (n, x). Thread-quad hq scans 16 h-values of columns x and x+1 in REGISTERS
// (32 independent up-front loads); LDS holds only 4KB of segment totals/firsts.
// Emits qbuf[n][h][x][c] = (I[h][x], I[h][x1], I[h1][x], I[h1][x1]), clamps baked in.
__global__ __launch_bounds__(256) void k_quadcol(const float* __restrict__ rowsum,
                                                 float4* __restrict__ qbuf)
{
    __shared__ float tA[4][C_CH], tB[4][C_CH];   // per-segment totals
    __shared__ float fA[4][C_CH], fB[4][C_CH];   // per-segment first raw elements
    const int x  = blockIdx.x;
    const int n  = blockIdx.y;
    const int x1 = min(x + 1, WF - 1);
    const int c  = threadIdx.x & 63;
    const int hq = threadIdx.x >> 6;

    const float* base0 = rowsum + (size_t)n*HF*WF*C_CH + (size_t)x  * C_CH + c;
    const float* base1 = rowsum + (size_t)n*HF*WF*C_CH + (size_t)x1 * C_CH + c;

    float eA[16], eB[16];
    #pragma unroll
    for (int i = 0; i < 16; ++i) {
        const int h = hq*16 + i;
        eA[i] = base0[(size_t)h * (WF*C_CH)];
        eB[i] = base1[(size_t)h * (WF*C_CH)];
    }
    float sA[16], sB[16];
    sA[0] = eA[0]; sB[0] = eB[0];
    #pragma unroll
    for (int i = 1; i < 16; ++i) {
        sA[i] = sA[i-1] + eA[i];
        sB[i] = sB[i-1] + eB[i];
    }
    tA[hq][c] = sA[15]; tB[hq][c] = sB[15];
    fA[hq][c] = eA[0];  fB[hq][c] = eB[0];
    __syncthreads();

    float offA = 0.0f, offB = 0.0f;
    #pragma unroll
    for (int s = 0; s < 3; ++s)
        if (s < hq) { offA += tA[s][c]; offB += tB[s][c]; }

    // boundary value A_final[(hq+1)*16] (clamped for hq==3 -> own last element)
    float nextA, nextB;
    if (hq < 3) {
        nextA = fA[hq+1][c] + (offA + tA[hq][c]);
        nextB = fB[hq+1][c] + (offB + tB[hq][c]);
    } else {
        nextA = sA[15] + offA;
        nextB = sB[15] + offB;
    }

    float4* qb = qbuf + ((size_t)n*HF*WF + x) * C_CH + c;
    #pragma unroll
    for (int i = 0; i < 16; ++i) {
        const int h = hq*16 + i;
        float4 q;
        q.x = sA[i] + offA;
        q.y = sB[i] + offB;
        if (i < 15) {
            q.z = sA[i+1] + offA;
            q.w = sB[i+1] + offB;
        } else {
            q.z = nextA;
            q.w = nextB;
        }
        qb[(size_t)h * (WF*C_CH)] = q;
    }
}

// ---------------- Kernel 3: project 8 voxel corners + bbox + quad offsets --------------
// One thread per (cam, nh, p). Recomputes the corner projections inline (cheap),
// eliminating the separate k_project pass and its ncbuf round-trip.
__global__ void k_boxproj(const float* __restrict__ ks,
                          const float* __restrict__ imu2cs,
                          const float* __restrict__ post_rots,
                          const float* __restrict__ post_trans,
                          const float* __restrict__ undists,
                          const float* __restrict__ grid,
                          BoxP* __restrict__ bp)
{
    const int idx = blockIdx.x * blockDim.x + threadIdx.x;
    if (idx >= NCAM * NH * NP) return;
    const int n  = idx / (NH * NP);
    const int r  = idx % (NH * NP);
    const int nh = r / NP;
    const int p  = r % NP;
    const int d  = p / WDIM;
    const int wd = p % WDIM;

    const float* k  = ks         + n * 9;
    const float* m  = imu2cs     + n * 12;
    const float* pr = post_rots  + n * 9;
    const float* pt = post_trans + n * 3;
    const float* D  = undists    + n * 7;

    float cal[12];
    #pragma unroll
    for (int i = 0; i < 3; ++i)
        #pragma unroll
        for (int j = 0; j < 4; ++j)
            cal[i*4+j] = k[i*3+0]*m[0*4+j] + k[i*3+1]*m[1*4+j] + k[i*3+2]*m[2*4+j];

    const float fx = k[0], fy = k[4], cx = k[2], cy = k[5];
    const bool fish = (D[6] == 1.0f);
    const float D0 = D[0], D1 = D[1], D2 = D[2], D3 = D[3], D4 = D[4], D5 = D[5];

    float left = 1e30f, right = -1e30f, top = 1e30f, bot = -1e30f;
    #pragma unroll
    for (int a = 0; a < 2; ++a) {
        const float vy = 2.0f - (float)(nh + a);   // ys = -arange(0,4)+2
        #pragma unroll
        for (int b = 0; b < 2; ++b) {
            #pragma unroll
            for (int cc = 0; cc < 2; ++cc) {
                const int gz = d + b, gx = wd + cc;
                const float vx = grid[(gz*GDIM + gx)*3 + 0];
                const float vz = grid[(gz*GDIM + gx)*3 + 2];

                const float hx = cal[0]*vx + cal[1]*vy + cal[2]*vz  + cal[3];
                const float hy = cal[4]*vx + cal[5]*vy + cal[6]*vz  + cal[7];
                const float hz = cal[8]*vx + cal[9]*vy + cal[10]*vz + cal[11];

                const float fl = (hz > 0.0f) ? 1.0f : 0.0f;
                const float px = (hx * fl) / hz;
                const float py = (hy * fl) / hz;

                const float x = (px - cx) / fx;
                const float y = (py - cy) / fy;

                float xd, yd;
                if (fish) {
                    const float rr = sqrtf(x*x + y*y);
                    const float th = atanf(rr);
                    const float t2 = th * th;
                    const float t4 = t2 * t2;
                    const float rad = th * (1.0f + D0*t2 + D1*t4 + D2*(t2*t4) + D5*(t4*t4)) / rr;
                    xd = x * rad * fx + cx;
                    yd = y * rad * fy + cy;
                } else {
                    const float r2 = x*x + y*y;
                    const float poly = 1.0f + D0*r2 + D1*r2*r2 + D2*r2*r2*r2;
                    const float xdd = x*poly + (2.0f*D3*x*y + D4*(r2 + 2.0f*x*x));
                    const float ydd = y*poly + (D3*(r2 + 2.0f*y*y) + 2.0f*D4*x*y);
                    xd = xdd * fx + cx;
                    yd = ydd * fy + cy;
                }
                xd *= fl; yd *= fl;

                const float qx = pr[0]*xd + pr[1]*yd + pt[0];
                const float qy = pr[3]*xd + pr[4]*yd + pt[1];
                const float ncx = fminf(fmaxf(2.0f*qx - 1.0f, -1.0f), 1.0f);
                const float ncy = fminf(fmaxf(2.0f*qy - 1.0f, -1.0f), 1.0f);

                left  = fminf(left,  ncx);  right = fmaxf(right, ncx);
                top   = fminf(top,   ncy);  bot   = fmaxf(bot,   ncy);
            }
        }
    }

    const float area = (right - left) * (bot - top) * (float)HF * (float)WF * 0.25f + 1e-6f;

    const float xLp = fminf(fmaxf((left  + 1.0f) * 0.5f * (float)(WF-1), 0.0f), (float)(WF-1));
    const float xRp = fminf(fmaxf((right + 1.0f) * 0.5f * (float)(WF-1), 0.0f), (float)(WF-1));
    const float yTp = fminf(fmaxf((top   + 1.0f) * 0.5f * (float)(HF-1), 0.0f), (float)(HF-1));
    const float yBp = fminf(fmaxf((bot   + 1.0f) * 0.5f * (float)(HF-1), 0.0f), (float)(HF-1));
    const float xL0 = floorf(xLp), xR0 = floorf(xRp), yT0 = floorf(yTp), yB0 = floorf(yBp);

    const int rT = (int)yT0 * (WF*C_CH*16);
    const int rB = (int)yB0 * (WF*C_CH*16);
    const int cL = (int)xL0 * (C_CH*16);
    const int cR = (int)xR0 * (C_CH*16);

    BoxP o;
    o.oTL = rT + cL; o.oTR = rT + cR; o.oBL = rB + cL; o.oBR = rB + cR;
    o.wxL = xLp - xL0; o.wxR = xRp - xR0; o.wyT = yTp - yT0; o.wyB = yBp - yB0;
    o.area = area; o.pad0 = 0; o.pad1 = 0; o.pad2 = 0;
    bp[idx] = o;
}

// ---------------- Kernel 4: sample quad texels, combine, max over cameras ----------------
// Wave per 8 voxels, lane = channel. BRANCHLESS fully-unrolled 6-camera body:
// all 24 dwordx4 loads issue up front (clipped cameras hit offset-0 border texels,
// which stay L1-resident). Gate applied as a cndmask on the result.
__global__ __launch_bounds__(256) void k_sample(const float4* __restrict__ qbuf,
                                                const BoxP* __restrict__ bp,
                                                float* __restrict__ out)
{
    __shared__ float sm[C_CH][33];
    const int nh   = blockIdx.y;
    const int p0   = blockIdx.x * 32;
    const int tid  = threadIdx.x;
    const int wave = __builtin_amdgcn_readfirstlane(tid >> 6);
    const int c    = tid & 63;

    #pragma unroll 1
    for (int j = 0; j < 8; ++j) {
        const int pj = p0 + wave*8 + j;
        const BoxP* bb = bp + nh*NP + pj;
        float vmax = -3.402823466e38f;
        #pragma unroll
        for (int n = 0; n < NCAM; ++n) {
            const BoxP* bpp = bb + n * (NH*NP);
            const float area = rfl_f(bpp->area);
            const int oTL = rfl_i(bpp->oTL), oTR = rfl_i(bpp->oTR);
            const int oBL = rfl_i(bpp->oBL), oBR = rfl_i(bpp->oBR);
            const float wxL = rfl_f(bpp->wxL), wxR = rfl_f(bpp->wxR);
            const float wyT = rfl_f(bpp->wyT), wyB = rfl_f(bpp->wyB);

            const char* qb = (const char*)qbuf + (size_t)n * ((size_t)HF*WF*C_CH*16);
            const float4 qTL = ((const float4*)(qb + (size_t)oTL))[c];
            const float4 qTR = ((const float4*)(qb + (size_t)oTR))[c];
            const float4 qBL = ((const float4*)(qb + (size_t)oBL))[c];
            const float4 qBR = ((const float4*)(qb + (size_t)oBR))[c];

            auto BIL = [&](const float4& q, float wx, float wy) -> float {
                const float m0 = fmaf(wx, q.y - q.x, q.x);
                const float m1 = fmaf(wx, q.w - q.z, q.z);
                return fmaf(wy, m1 - m0, m0);
            };
            const float tl = BIL(qTL, wxL, wyT);
            const float tr = BIL(qTR, wxR, wyT);
            const float bl = BIL(qBL, wxL, wyB);
            const float br = BIL(qBR, wxR, wyB);
            const float s  = (tl + br) - (tr + bl);
            float v = s * __builtin_amdgcn_rcpf(area);
            v = (area > 1e-6f) ? v : 0.0f;      // reference: vox * (area > EPS)
            vmax = fmaxf(vmax, v);
        }
        sm[c][wave*8 + j] = vmax;
    }
    __syncthreads();
    for (int idx = tid; idx < C_CH * 32; idx += 256) {
        const int cc = idx >> 5;
        const int jj = idx & 31;
        out[(size_t)(cc*NH + nh)*NP + p0 + jj] = sm[cc][jj];
    }
}

extern "C" void kernel_launch(void* const* d_in, const int* in_sizes, int n_in,
                              void* d_out, int out_size, void* d_ws, size_t ws_size,
                              hipStream_t stream)
{
    const float* feats      = (const float*)d_in[0];  // [1,6,64,64,176]
    const float* ks         = (const float*)d_in[1];  // [1,6,3,3]
    const float* imu2cs     = (const float*)d_in[2];  // [1,6,3,4]
    const float* post_rots  = (const float*)d_in[3];  // [1,6,3,3]
    const float* post_trans = (const float*)d_in[4];  // [1,6,3]
    const float* undists    = (const float*)d_in[5];  // [1,6,7]
    const float* grid       = (const float*)d_in[6];  // [1,129,129,3]
    float* out = (float*)d_out;                       // [1,192,128,128]

    char* ws = (char*)d_ws;
    size_t off = 0;
    float* rowsum = (float*)(ws + off);
    off += sizeof(float) * NCAM * HF * WF * C_CH;
    off = (off + 255) & ~(size_t)255;
    float4* qbuf = (float4*)(ws + off);
    off += sizeof(float4) * (size_t)NCAM * HF * WF * C_CH;
    off = (off + 255) & ~(size_t)255;
    BoxP* bp = (BoxP*)(ws + off);
    off += sizeof(BoxP) * NCAM * NH * NP;
    (void)ws_size; (void)in_sizes; (void)n_in; (void)out_size;

    dim3 g1(HF, NCAM);
    k_rowcum<<<g1, 256, 0, stream>>>(feats, rowsum);

    dim3 g2(WF, NCAM);
    k_quadcol<<<g2, 256, 0, stream>>>(rowsum, qbuf);

    dim3 g3((NCAM*NH*NP + 255)/256);
    k_boxproj<<<g3, 256, 0, stream>>>(ks, imu2cs, post_rots, post_trans, undists, grid, bp);

    dim3 g4(NP/32, NH);
    k_sample<<<g4, 256, 0, stream>>>(qbuf, bp, out);
}